// Round 5
// baseline (460.741 us; speedup 1.0000x reference)
//
#include <hip/hip_runtime.h>

// ---------------------------------------------------------------------------
// MultiheadSelfAttention (row-local head-mixing variant), MI355X / gfx950.
// Round 5: revert cooperative launch (launch was rejected -> zeros).
// GEMMs now use VGPR-staged software pipeline: global_load_dwordx4 for tile
// k+1 issued before compute(k), ds_write after -> vmcnt wait overlaps MFMA
// instead of draining at the barrier (the documented m97 ~20% stall).
// ---------------------------------------------------------------------------

typedef __bf16 bf16x8 __attribute__((ext_vector_type(8)));
typedef float  f32x16 __attribute__((ext_vector_type(16)));

__device__ __forceinline__ unsigned short f2b(float f) {
    unsigned int u = __builtin_bit_cast(unsigned int, f);
    return (unsigned short)((u + 0x7FFFu + ((u >> 16) & 1u)) >> 16);  // RNE
}
__device__ __forceinline__ unsigned int pack2(float a, float b) {
    return (unsigned int)f2b(a) | ((unsigned int)f2b(b) << 16);
}
__device__ __forceinline__ void unpack8(uint4 u, float* f) {
    unsigned int w[4] = {u.x, u.y, u.z, u.w};
#pragma unroll
    for (int a = 0; a < 4; ++a) {
        union { unsigned int i; float f; } lo, hi;
        lo.i = w[a] << 16;
        hi.i = w[a] & 0xFFFF0000u;
        f[a * 2]     = lo.f;
        f[a * 2 + 1] = hi.f;
    }
}

// ------------------------- fused fp32 -> bf16 cast -------------------------
__global__ __launch_bounds__(256) void cvt_all(const float* __restrict__ x,
                                               const float* __restrict__ wqkv,
                                               const float* __restrict__ wproj,
                                               unsigned short* __restrict__ xb,
                                               unsigned short* __restrict__ wqkvb,
                                               unsigned short* __restrict__ wprojb) {
    int i = blockIdx.x * 256 + threadIdx.x;
    const float* src;
    unsigned short* dst;
    if (i < 2097152)      { src = x;     dst = xb;                   }
    else if (i < 2883584) { src = wqkv;  dst = wqkvb;  i -= 2097152; }
    else                  { src = wproj; dst = wprojb; i -= 2883584; }
    float4 f = reinterpret_cast<const float4*>(src)[i];
    ushort4 u;
    u.x = f2b(f.x); u.y = f2b(f.y); u.z = f2b(f.z); u.w = f2b(f.w);
    reinterpret_cast<ushort4*>(dst)[i] = u;
}

// ------------------- bf16 NT GEMM, VGPR-staged pipeline --------------------
// C[m,n] = sum_k A[m,k]*B[n,k].  A: MxK rm, B: NxK rm (bf16 bits as ushort).
// 128x128 tile, BK=64, 4 waves 2x2, wave tile 64x64 as 2x2 of 32x32x16 MFMA.
// LDS rows = 8 chunks of 16B; chunk c of row r at slot c^(r&7) (conflict-free
// ds_read_b128 and ds_write_b128).  Pipeline per k-step:
//   barrier | issue global loads k+1 -> regs | compute(k) | barrier |
//   ds_write regs -> LDS   (s_waitcnt vmcnt lands here, after compute)
__device__ __forceinline__ void store_c(float* C, long idx, float v)          { C[idx] = v; }
__device__ __forceinline__ void store_c(unsigned short* C, long idx, float v) { C[idx] = f2b(v); }

template <typename CT>
__global__ __launch_bounds__(256, 3) void gemm_bt(const unsigned short* __restrict__ A,
                                                  const unsigned short* __restrict__ B,
                                                  CT* __restrict__ C,
                                                  int M, int N, int K) {
    __shared__ __align__(16) unsigned short As[128 * 64];
    __shared__ __align__(16) unsigned short Bs[128 * 64];

    const int tid  = threadIdx.x;
    const int lane = tid & 63;
    const int wave = tid >> 6;
    const long bm  = blockIdx.y;
    const long bn  = blockIdx.x;
    const int wm   = (wave >> 1) * 64;
    const int wn   = (wave & 1) * 64;

    f32x16 acc[2][2] = {};

    const int srow  = tid >> 3;                        // row within 32-row group
    const int sgcol = ((tid & 7) ^ (srow & 7)) << 3;   // swizzled SOURCE chunk

    const unsigned short* aptr = A + bm * 128 * (long)K + (long)srow * K + sgcol;
    const unsigned short* bptr = B + bn * 128 * (long)K + (long)srow * K + sgcol;

    uint4 areg[4], breg[4];
#pragma unroll
    for (int r = 0; r < 4; ++r) areg[r] = *reinterpret_cast<const uint4*>(aptr + (long)r * 32 * K);
#pragma unroll
    for (int r = 0; r < 4; ++r) breg[r] = *reinterpret_cast<const uint4*>(bptr + (long)r * 32 * K);
#pragma unroll
    for (int r = 0; r < 4; ++r) *reinterpret_cast<uint4*>(As + (r * 256 + tid) * 8) = areg[r];
#pragma unroll
    for (int r = 0; r < 4; ++r) *reinterpret_cast<uint4*>(Bs + (r * 256 + tid) * 8) = breg[r];

    for (int k0 = 0; k0 < K; k0 += 64) {
        __syncthreads();   // staging writes visible

        // issue next tile's global loads (unconditional; clamp on last iter)
        const int kload = (k0 + 64 < K) ? (k0 + 64) : 0;
#pragma unroll
        for (int r = 0; r < 4; ++r) areg[r] = *reinterpret_cast<const uint4*>(aptr + (long)r * 32 * K + kload);
#pragma unroll
        for (int r = 0; r < 4; ++r) breg[r] = *reinterpret_cast<const uint4*>(bptr + (long)r * 32 * K + kload);

        // compute on current LDS tile
        const int arow = lane & 31;
        const int kh   = lane >> 5;                    // k-half: k = kh*8 + j
#pragma unroll
        for (int kk = 0; kk < 4; ++kk) {               // 4 x K=16
            const int c  = kk * 2 + kh;                // logical chunk 0..7
            const int sw = (c ^ (lane & 7)) << 3;      // swizzled read offset
            bf16x8 af[2], bfr[2];
#pragma unroll
            for (int i = 0; i < 2; ++i)
                af[i] = *reinterpret_cast<const bf16x8*>(As + (wm + i * 32 + arow) * 64 + sw);
#pragma unroll
            for (int j = 0; j < 2; ++j)
                bfr[j] = *reinterpret_cast<const bf16x8*>(Bs + (wn + j * 32 + arow) * 64 + sw);
#pragma unroll
            for (int i = 0; i < 2; ++i)
#pragma unroll
                for (int j = 0; j < 2; ++j)
                    acc[i][j] = __builtin_amdgcn_mfma_f32_32x32x16_bf16(af[i], bfr[j], acc[i][j], 0, 0, 0);
        }
        __syncthreads();   // all LDS reads done; safe to overwrite

        // consume the in-flight loads (vmcnt wait lands here, after compute)
#pragma unroll
        for (int r = 0; r < 4; ++r) *reinterpret_cast<uint4*>(As + (r * 256 + tid) * 8) = areg[r];
#pragma unroll
        for (int r = 0; r < 4; ++r) *reinterpret_cast<uint4*>(Bs + (r * 256 + tid) * 8) = breg[r];
    }

    // C/D layout (verified m74/m101): col=lane&31, row=(r&3)+8*(r>>2)+4*(lane>>5)
    const long mbase = bm * 128 + wm + ((lane >> 5) << 2);
    const long nbase = bn * 128 + wn + (lane & 31);
#pragma unroll
    for (int i = 0; i < 2; ++i)
#pragma unroll
        for (int j = 0; j < 2; ++j)
#pragma unroll
            for (int r = 0; r < 16; ++r) {
                const long row = mbase + i * 32 + (r & 3) + 8 * (r >> 2);
                store_c(C, row * (long)N + nbase + j * 32, acc[i][j][r]);
            }
}

// ------------------- per-row head attention + scatter ----------------------
// qkv row m=(b,t): q=e[0,1024), k=e[1024,2048), v=e[2048,3072); h=e/64%16.
// scores[i][j]=0.125*dot64(q_i,k_j); softmax over j; out[i][s]=sum_j a*v.
// Scatter: out[b,t,h,s] -> out3[b, h*128 + t/16, 64*(t%16)+s].
// rows[] XOR chunk-swizzled: chunk c of 64-elem vector vi at c^(vi&7).
__global__ __launch_bounds__(256) void attn_rowlocal(const unsigned short* __restrict__ qkv,
                                                     unsigned short* __restrict__ out3) {
    __shared__ __align__(16) unsigned short rows[4 * 3072];  // 24 KB, swizzled
    __shared__ float attnS[4][16][17];                       // padded

    const int tid  = threadIdx.x;
    const int lane = tid & 63;
    const int wave = tid >> 6;
    const int m0   = blockIdx.x * 4;

    {   // cooperative load: LDS slot S gets global chunk (S&~7)|((S&7)^((S>>3)&7))
        const uint4* src = reinterpret_cast<const uint4*>(qkv + (long)m0 * 3072);
        uint4* dst = reinterpret_cast<uint4*>(rows);
#pragma unroll
        for (int c = 0; c < 6; ++c) {
            const int S  = c * 256 + tid;
            const int gs = (S & ~7) | ((S & 7) ^ ((S >> 3) & 7));
            dst[S] = src[gs];
        }
    }
    __syncthreads();

    const int m = m0 + wave;
    const int b = m >> 11;
    const int t = m & 2047;
    const unsigned short* rw = rows + wave * 3072;

    // scores: lane handles i = lane&15, j in [(lane>>4)*4, +4)
    const int i  = lane & 15;
    const int j0 = (lane >> 4) << 2;
    float sc[4] = {0.f, 0.f, 0.f, 0.f};
#pragma unroll
    for (int c8 = 0; c8 < 8; ++c8) {
        uint4 qu = *reinterpret_cast<const uint4*>(rw + i * 64 + ((c8 ^ (i & 7)) << 3));
        float qf[8];
        unpack8(qu, qf);
#pragma unroll
        for (int jj = 0; jj < 4; ++jj) {
            const int vi = 16 + j0 + jj;
            uint4 ku = *reinterpret_cast<const uint4*>(rw + vi * 64 + ((c8 ^ (vi & 7)) << 3));
            float kf[8];
            unpack8(ku, kf);
#pragma unroll
            for (int d = 0; d < 8; ++d) sc[jj] += qf[d] * kf[d];
        }
    }
#pragma unroll
    for (int jj = 0; jj < 4; ++jj) sc[jj] *= 0.125f;

    float mx = fmaxf(fmaxf(sc[0], sc[1]), fmaxf(sc[2], sc[3]));
    mx = fmaxf(mx, __shfl_xor(mx, 16));
    mx = fmaxf(mx, __shfl_xor(mx, 32));
    float sum = 0.f;
#pragma unroll
    for (int jj = 0; jj < 4; ++jj) { sc[jj] = __expf(sc[jj] - mx); sum += sc[jj]; }
    sum += __shfl_xor(sum, 16);
    sum += __shfl_xor(sum, 32);
    const float inv = 1.0f / sum;
#pragma unroll
    for (int jj = 0; jj < 4; ++jj) attnS[wave][i][j0 + jj] = sc[jj] * inv;
    __syncthreads();

    // out: lane handles head oi = lane>>2, s chunk s0 = (lane&3)*16
    const int oi = lane >> 2;
    const int s0 = (lane & 3) << 4;
    const int c0 = (lane & 3) << 1;
    float o[16];
#pragma unroll
    for (int ss = 0; ss < 16; ++ss) o[ss] = 0.f;
#pragma unroll
    for (int j = 0; j < 16; ++j) {
        const float a  = attnS[wave][oi][j];
        const int   vi = 32 + j;
        uint4 v0 = *reinterpret_cast<const uint4*>(rw + vi * 64 + (((c0)     ^ (vi & 7)) << 3));
        uint4 v1 = *reinterpret_cast<const uint4*>(rw + vi * 64 + (((c0 + 1) ^ (vi & 7)) << 3));
        float vf[16];
        unpack8(v0, vf);
        unpack8(v1, vf + 8);
#pragma unroll
        for (int ss = 0; ss < 16; ++ss) o[ss] += a * vf[ss];
    }

    uint4 r0, r1;
    r0.x = pack2(o[0],  o[1]);  r0.y = pack2(o[2],  o[3]);
    r0.z = pack2(o[4],  o[5]);  r0.w = pack2(o[6],  o[7]);
    r1.x = pack2(o[8],  o[9]);  r1.y = pack2(o[10], o[11]);
    r1.z = pack2(o[12], o[13]); r1.w = pack2(o[14], o[15]);

    const long base = (long)b * (2048 * 1024)
                    + (long)(oi * 128 + (t >> 4)) * 1024
                    + 64 * (t & 15) + s0;
    *reinterpret_cast<uint4*>(out3 + base)     = r0;
    *reinterpret_cast<uint4*>(out3 + base + 8) = r1;
}

// ------------------------------- launcher ----------------------------------
extern "C" void kernel_launch(void* const* d_in, const int* in_sizes, int n_in,
                              void* d_out, int out_size, void* d_ws, size_t ws_size,
                              hipStream_t stream) {
    const float* x     = (const float*)d_in[0];   // (4,2048,1024)
    const float* Wqkv  = (const float*)d_in[1];   // (3072,1024)
    const float* Wproj = (const float*)d_in[2];   // (1024,1024)
    float* out = (float*)d_out;                   // (4,2048,1024) fp32

    char* ws = (char*)d_ws;
    unsigned short* xb     = (unsigned short*)(ws);               // 16.0 MiB
    unsigned short* wqkvb  = (unsigned short*)(ws + 16777216);    //  6.0 MiB
    unsigned short* wprojb = (unsigned short*)(ws + 23068672);    //  2.0 MiB
    unsigned short* qkvb   = (unsigned short*)(ws + 25165824);    // 48.0 MiB
    unsigned short* out3b  = (unsigned short*)(ws + 75497472);    // 16.0 MiB

    // all three fp32->bf16 casts in one dispatch (3,145,728 float4s)
    cvt_all<<<dim3(12288), dim3(256), 0, stream>>>(x, Wqkv, Wproj, xb, wqkvb, wprojb);

    // qkv = x @ Wqkv^T : M=8192, N=3072, K=1024
    gemm_bt<unsigned short><<<dim3(24, 64), dim3(256), 0, stream>>>(
        xb, wqkvb, qkvb, 8192, 3072, 1024);

    attn_rowlocal<<<dim3(2048), dim3(256), 0, stream>>>(qkvb, out3b);

    // out = out3 @ Wproj^T : M=8192, N=1024, K=1024
    gemm_bt<float><<<dim3(8, 64), dim3(256), 0, stream>>>(
        out3b, wprojb, out, 8192, 1024, 1024);
}

// Round 6
// 435.237 us; speedup vs baseline: 1.0586x; 1.0586x over previous
//
#include <hip/hip_runtime.h>

// ---------------------------------------------------------------------------
// MultiheadSelfAttention (row-local head-mixing variant), MI355X / gfx950.
// Round 6: retry VGPR-staged GEMM pipeline WITHOUT __launch_bounds__ min-wave
// bound (R5's (256,3) cap made the allocator spill 8xuint4 staging to scratch
// -> 812 MB HBM writes).  Everything else identical to R5/R3.
// ---------------------------------------------------------------------------

typedef __bf16 bf16x8 __attribute__((ext_vector_type(8)));
typedef float  f32x16 __attribute__((ext_vector_type(16)));

__device__ __forceinline__ unsigned short f2b(float f) {
    unsigned int u = __builtin_bit_cast(unsigned int, f);
    return (unsigned short)((u + 0x7FFFu + ((u >> 16) & 1u)) >> 16);  // RNE
}
__device__ __forceinline__ unsigned int pack2(float a, float b) {
    return (unsigned int)f2b(a) | ((unsigned int)f2b(b) << 16);
}
__device__ __forceinline__ void unpack8(uint4 u, float* f) {
    unsigned int w[4] = {u.x, u.y, u.z, u.w};
#pragma unroll
    for (int a = 0; a < 4; ++a) {
        union { unsigned int i; float f; } lo, hi;
        lo.i = w[a] << 16;
        hi.i = w[a] & 0xFFFF0000u;
        f[a * 2]     = lo.f;
        f[a * 2 + 1] = hi.f;
    }
}

// ------------------------- fused fp32 -> bf16 cast -------------------------
__global__ __launch_bounds__(256) void cvt_all(const float* __restrict__ x,
                                               const float* __restrict__ wqkv,
                                               const float* __restrict__ wproj,
                                               unsigned short* __restrict__ xb,
                                               unsigned short* __restrict__ wqkvb,
                                               unsigned short* __restrict__ wprojb) {
    int i = blockIdx.x * 256 + threadIdx.x;
    const float* src;
    unsigned short* dst;
    if (i < 2097152)      { src = x;     dst = xb;                   }
    else if (i < 2883584) { src = wqkv;  dst = wqkvb;  i -= 2097152; }
    else                  { src = wproj; dst = wprojb; i -= 2883584; }
    float4 f = reinterpret_cast<const float4*>(src)[i];
    ushort4 u;
    u.x = f2b(f.x); u.y = f2b(f.y); u.z = f2b(f.z); u.w = f2b(f.w);
    reinterpret_cast<ushort4*>(dst)[i] = u;
}

// ------------------- bf16 NT GEMM, VGPR-staged pipeline --------------------
// C[m,n] = sum_k A[m,k]*B[n,k].  A: MxK rm, B: NxK rm (bf16 bits as ushort).
// 128x128 tile, BK=64, 4 waves 2x2, wave tile 64x64 as 2x2 of 32x32x16 MFMA.
// LDS rows = 8 chunks of 16B; chunk c of row r at slot c^(r&7) (conflict-free
// ds_read_b128 and ds_write_b128).  Pipeline per k-step:
//   barrier | issue global loads k+1 -> regs | compute(k) | barrier |
//   ds_write regs -> LDS   (s_waitcnt vmcnt lands after compute, not before)
__device__ __forceinline__ void store_c(float* C, long idx, float v)          { C[idx] = v; }
__device__ __forceinline__ void store_c(unsigned short* C, long idx, float v) { C[idx] = f2b(v); }

template <typename CT>
__global__ __launch_bounds__(256) void gemm_bt(const unsigned short* __restrict__ A,
                                               const unsigned short* __restrict__ B,
                                               CT* __restrict__ C,
                                               int M, int N, int K) {
    __shared__ __align__(16) unsigned short As[128 * 64];
    __shared__ __align__(16) unsigned short Bs[128 * 64];

    const int tid  = threadIdx.x;
    const int lane = tid & 63;
    const int wave = tid >> 6;
    const long bm  = blockIdx.y;
    const long bn  = blockIdx.x;
    const int wm   = (wave >> 1) * 64;
    const int wn   = (wave & 1) * 64;

    f32x16 acc[2][2] = {};

    const int srow  = tid >> 3;                        // row within 32-row group
    const int sgcol = ((tid & 7) ^ (srow & 7)) << 3;   // swizzled SOURCE chunk

    const unsigned short* aptr = A + bm * 128 * (long)K + (long)srow * K + sgcol;
    const unsigned short* bptr = B + bn * 128 * (long)K + (long)srow * K + sgcol;

    uint4 areg[4], breg[4];
#pragma unroll
    for (int r = 0; r < 4; ++r) areg[r] = *reinterpret_cast<const uint4*>(aptr + (long)r * 32 * K);
#pragma unroll
    for (int r = 0; r < 4; ++r) breg[r] = *reinterpret_cast<const uint4*>(bptr + (long)r * 32 * K);
#pragma unroll
    for (int r = 0; r < 4; ++r) *reinterpret_cast<uint4*>(As + (r * 256 + tid) * 8) = areg[r];
#pragma unroll
    for (int r = 0; r < 4; ++r) *reinterpret_cast<uint4*>(Bs + (r * 256 + tid) * 8) = breg[r];

    for (int k0 = 0; k0 < K; k0 += 64) {
        __syncthreads();   // staging writes visible

        // issue next tile's global loads (unconditional; clamp on last iter)
        const int kload = (k0 + 64 < K) ? (k0 + 64) : 0;
#pragma unroll
        for (int r = 0; r < 4; ++r) areg[r] = *reinterpret_cast<const uint4*>(aptr + (long)r * 32 * K + kload);
#pragma unroll
        for (int r = 0; r < 4; ++r) breg[r] = *reinterpret_cast<const uint4*>(bptr + (long)r * 32 * K + kload);

        // compute on current LDS tile
        const int arow = lane & 31;
        const int kh   = lane >> 5;                    // k-half: k = kh*8 + j
#pragma unroll
        for (int kk = 0; kk < 4; ++kk) {               // 4 x K=16
            const int c  = kk * 2 + kh;                // logical chunk 0..7
            const int sw = (c ^ (lane & 7)) << 3;      // swizzled read offset
            bf16x8 af[2], bfr[2];
#pragma unroll
            for (int i = 0; i < 2; ++i)
                af[i] = *reinterpret_cast<const bf16x8*>(As + (wm + i * 32 + arow) * 64 + sw);
#pragma unroll
            for (int j = 0; j < 2; ++j)
                bfr[j] = *reinterpret_cast<const bf16x8*>(Bs + (wn + j * 32 + arow) * 64 + sw);
#pragma unroll
            for (int i = 0; i < 2; ++i)
#pragma unroll
                for (int j = 0; j < 2; ++j)
                    acc[i][j] = __builtin_amdgcn_mfma_f32_32x32x16_bf16(af[i], bfr[j], acc[i][j], 0, 0, 0);
        }
        __syncthreads();   // all LDS reads done; safe to overwrite

        // consume in-flight loads (vmcnt wait lands here, after compute)
#pragma unroll
        for (int r = 0; r < 4; ++r) *reinterpret_cast<uint4*>(As + (r * 256 + tid) * 8) = areg[r];
#pragma unroll
        for (int r = 0; r < 4; ++r) *reinterpret_cast<uint4*>(Bs + (r * 256 + tid) * 8) = breg[r];
    }

    // C/D layout (verified m74/m101): col=lane&31, row=(r&3)+8*(r>>2)+4*(lane>>5)
    const long mbase = bm * 128 + wm + ((lane >> 5) << 2);
    const long nbase = bn * 128 + wn + (lane & 31);
#pragma unroll
    for (int i = 0; i < 2; ++i)
#pragma unroll
        for (int j = 0; j < 2; ++j)
#pragma unroll
            for (int r = 0; r < 16; ++r) {
                const long row = mbase + i * 32 + (r & 3) + 8 * (r >> 2);
                store_c(C, row * (long)N + nbase + j * 32, acc[i][j][r]);
            }
}

// ------------------- per-row head attention + scatter ----------------------
// qkv row m=(b,t): q=e[0,1024), k=e[1024,2048), v=e[2048,3072); h=e/64%16.
// scores[i][j]=0.125*dot64(q_i,k_j); softmax over j; out[i][s]=sum_j a*v.
// Scatter: out[b,t,h,s] -> out3[b, h*128 + t/16, 64*(t%16)+s].
// rows[] XOR chunk-swizzled: chunk c of 64-elem vector vi at c^(vi&7).
__global__ __launch_bounds__(256) void attn_rowlocal(const unsigned short* __restrict__ qkv,
                                                     unsigned short* __restrict__ out3) {
    __shared__ __align__(16) unsigned short rows[4 * 3072];  // 24 KB, swizzled
    __shared__ float attnS[4][16][17];                       // padded

    const int tid  = threadIdx.x;
    const int lane = tid & 63;
    const int wave = tid >> 6;
    const int m0   = blockIdx.x * 4;

    {   // cooperative load: LDS slot S gets global chunk (S&~7)|((S&7)^((S>>3)&7))
        const uint4* src = reinterpret_cast<const uint4*>(qkv + (long)m0 * 3072);
        uint4* dst = reinterpret_cast<uint4*>(rows);
#pragma unroll
        for (int c = 0; c < 6; ++c) {
            const int S  = c * 256 + tid;
            const int gs = (S & ~7) | ((S & 7) ^ ((S >> 3) & 7));
            dst[S] = src[gs];
        }
    }
    __syncthreads();

    const int m = m0 + wave;
    const int b = m >> 11;
    const int t = m & 2047;
    const unsigned short* rw = rows + wave * 3072;

    // scores: lane handles i = lane&15, j in [(lane>>4)*4, +4)
    const int i  = lane & 15;
    const int j0 = (lane >> 4) << 2;
    float sc[4] = {0.f, 0.f, 0.f, 0.f};
#pragma unroll
    for (int c8 = 0; c8 < 8; ++c8) {
        uint4 qu = *reinterpret_cast<const uint4*>(rw + i * 64 + ((c8 ^ (i & 7)) << 3));
        float qf[8];
        unpack8(qu, qf);
#pragma unroll
        for (int jj = 0; jj < 4; ++jj) {
            const int vi = 16 + j0 + jj;
            uint4 ku = *reinterpret_cast<const uint4*>(rw + vi * 64 + ((c8 ^ (vi & 7)) << 3));
            float kf[8];
            unpack8(ku, kf);
#pragma unroll
            for (int d = 0; d < 8; ++d) sc[jj] += qf[d] * kf[d];
        }
    }
#pragma unroll
    for (int jj = 0; jj < 4; ++jj) sc[jj] *= 0.125f;

    float mx = fmaxf(fmaxf(sc[0], sc[1]), fmaxf(sc[2], sc[3]));
    mx = fmaxf(mx, __shfl_xor(mx, 16));
    mx = fmaxf(mx, __shfl_xor(mx, 32));
    float sum = 0.f;
#pragma unroll
    for (int jj = 0; jj < 4; ++jj) { sc[jj] = __expf(sc[jj] - mx); sum += sc[jj]; }
    sum += __shfl_xor(sum, 16);
    sum += __shfl_xor(sum, 32);
    const float inv = 1.0f / sum;
#pragma unroll
    for (int jj = 0; jj < 4; ++jj) attnS[wave][i][j0 + jj] = sc[jj] * inv;
    __syncthreads();

    // out: lane handles head oi = lane>>2, s chunk s0 = (lane&3)*16
    const int oi = lane >> 2;
    const int s0 = (lane & 3) << 4;
    const int c0 = (lane & 3) << 1;
    float o[16];
#pragma unroll
    for (int ss = 0; ss < 16; ++ss) o[ss] = 0.f;
#pragma unroll
    for (int j = 0; j < 16; ++j) {
        const float a  = attnS[wave][oi][j];
        const int   vi = 32 + j;
        uint4 v0 = *reinterpret_cast<const uint4*>(rw + vi * 64 + (((c0)     ^ (vi & 7)) << 3));
        uint4 v1 = *reinterpret_cast<const uint4*>(rw + vi * 64 + (((c0 + 1) ^ (vi & 7)) << 3));
        float vf[16];
        unpack8(v0, vf);
        unpack8(v1, vf + 8);
#pragma unroll
        for (int ss = 0; ss < 16; ++ss) o[ss] += a * vf[ss];
    }

    uint4 r0, r1;
    r0.x = pack2(o[0],  o[1]);  r0.y = pack2(o[2],  o[3]);
    r0.z = pack2(o[4],  o[5]);  r0.w = pack2(o[6],  o[7]);
    r1.x = pack2(o[8],  o[9]);  r1.y = pack2(o[10], o[11]);
    r1.z = pack2(o[12], o[13]); r1.w = pack2(o[14], o[15]);

    const long base = (long)b * (2048 * 1024)
                    + (long)(oi * 128 + (t >> 4)) * 1024
                    + 64 * (t & 15) + s0;
    *reinterpret_cast<uint4*>(out3 + base)     = r0;
    *reinterpret_cast<uint4*>(out3 + base + 8) = r1;
}

// ------------------------------- launcher ----------------------------------
extern "C" void kernel_launch(void* const* d_in, const int* in_sizes, int n_in,
                              void* d_out, int out_size, void* d_ws, size_t ws_size,
                              hipStream_t stream) {
    const float* x     = (const float*)d_in[0];   // (4,2048,1024)
    const float* Wqkv  = (const float*)d_in[1];   // (3072,1024)
    const float* Wproj = (const float*)d_in[2];   // (1024,1024)
    float* out = (float*)d_out;                   // (4,2048,1024) fp32

    char* ws = (char*)d_ws;
    unsigned short* xb     = (unsigned short*)(ws);               // 16.0 MiB
    unsigned short* wqkvb  = (unsigned short*)(ws + 16777216);    //  6.0 MiB
    unsigned short* wprojb = (unsigned short*)(ws + 23068672);    //  2.0 MiB
    unsigned short* qkvb   = (unsigned short*)(ws + 25165824);    // 48.0 MiB
    unsigned short* out3b  = (unsigned short*)(ws + 75497472);    // 16.0 MiB

    // all three fp32->bf16 casts in one dispatch (3,145,728 float4s)
    cvt_all<<<dim3(12288), dim3(256), 0, stream>>>(x, Wqkv, Wproj, xb, wqkvb, wprojb);

    // qkv = x @ Wqkv^T : M=8192, N=3072, K=1024
    gemm_bt<unsigned short><<<dim3(24, 64), dim3(256), 0, stream>>>(
        xb, wqkvb, qkvb, 8192, 3072, 1024);

    attn_rowlocal<<<dim3(2048), dim3(256), 0, stream>>>(qkvb, out3b);

    // out = out3 @ Wproj^T : M=8192, N=1024, K=1024
    gemm_bt<float><<<dim3(8, 64), dim3(256), 0, stream>>>(
        out3b, wprojb, out, 8192, 1024, 1024);
}

// Round 7
// 198.891 us; speedup vs baseline: 2.3165x; 2.1883x over previous
//
#include <hip/hip_runtime.h>

// ---------------------------------------------------------------------------
// MultiheadSelfAttention (row-local head-mixing variant), MI355X / gfx950.
// Round 7: exact revert to R3 (best measured: 199.1 us).  R5/R6 established
// that VGPR-staged K-loop pipelining spills (compiler holds ~76-128 reg
// budget; 884 MB scratch traffic) — the m97-structure plateau stands.
// GEMM1: 812 TF, conflict-free swizzled LDS, 32x32x16 MFMA, global_load_lds.
// ---------------------------------------------------------------------------

typedef __bf16 bf16x8 __attribute__((ext_vector_type(8)));
typedef float  f32x16 __attribute__((ext_vector_type(16)));

typedef __attribute__((address_space(3))) void       lds_void;
typedef const __attribute__((address_space(1))) void gbl_void;

__device__ __forceinline__ unsigned short f2b(float f) {
    unsigned int u = __builtin_bit_cast(unsigned int, f);
    return (unsigned short)((u + 0x7FFFu + ((u >> 16) & 1u)) >> 16);  // RNE
}
__device__ __forceinline__ unsigned int pack2(float a, float b) {
    return (unsigned int)f2b(a) | ((unsigned int)f2b(b) << 16);
}
__device__ __forceinline__ void unpack8(uint4 u, float* f) {
    unsigned int w[4] = {u.x, u.y, u.z, u.w};
#pragma unroll
    for (int a = 0; a < 4; ++a) {
        union { unsigned int i; float f; } lo, hi;
        lo.i = w[a] << 16;
        hi.i = w[a] & 0xFFFF0000u;
        f[a * 2]     = lo.f;
        f[a * 2 + 1] = hi.f;
    }
}

// ------------------------- fused fp32 -> bf16 cast -------------------------
// One grid covers x (2097152 f4), Wqkv (786432 f4), Wproj (262144 f4).
__global__ __launch_bounds__(256) void cvt_all(const float* __restrict__ x,
                                               const float* __restrict__ wqkv,
                                               const float* __restrict__ wproj,
                                               unsigned short* __restrict__ xb,
                                               unsigned short* __restrict__ wqkvb,
                                               unsigned short* __restrict__ wprojb) {
    int i = blockIdx.x * 256 + threadIdx.x;
    const float* src;
    unsigned short* dst;
    if (i < 2097152)      { src = x;     dst = xb;                   }
    else if (i < 2883584) { src = wqkv;  dst = wqkvb;  i -= 2097152; }
    else                  { src = wproj; dst = wprojb; i -= 2883584; }
    float4 f = reinterpret_cast<const float4*>(src)[i];
    ushort4 u;
    u.x = f2b(f.x); u.y = f2b(f.y); u.z = f2b(f.z); u.w = f2b(f.w);
    reinterpret_cast<ushort4*>(dst)[i] = u;
}

// --------------------------- bf16 NT GEMM ----------------------------------
// C[m,n] = sum_k A[m,k]*B[n,k].  A: MxK rm, B: NxK rm (bf16 bits as ushort).
// Block tile 128x128, BK=64.  4 waves 2x2; wave tile 64x64 as 2x2 tiles of
// 32x32x16 MFMA.  LDS rows are 8 chunks of 16B; chunk c of row r at slot
// c^(r&7) -> conflict-free ds_read_b128 and conflict-free staging.
__device__ __forceinline__ void store_c(float* C, long idx, float v)          { C[idx] = v; }
__device__ __forceinline__ void store_c(unsigned short* C, long idx, float v) { C[idx] = f2b(v); }

template <typename CT>
__global__ __launch_bounds__(256) void gemm_bt(const unsigned short* __restrict__ A,
                                               const unsigned short* __restrict__ B,
                                               CT* __restrict__ C,
                                               int M, int N, int K) {
    __shared__ __align__(16) unsigned short As[128 * 64];
    __shared__ __align__(16) unsigned short Bs[128 * 64];

    const int tid  = threadIdx.x;
    const int lane = tid & 63;
    const int wave = tid >> 6;
    const long bm  = blockIdx.y;
    const long bn  = blockIdx.x;
    const int wm   = (wave >> 1) * 64;
    const int wn   = (wave & 1) * 64;

    f32x16 acc[2][2] = {};

    const unsigned short* Ab = A + bm * 128 * (long)K;
    const unsigned short* Bb = B + bn * 128 * (long)K;

    const int srow  = tid >> 3;                        // row within 32-row group
    const int sgcol = ((tid & 7) ^ (srow & 7)) << 3;   // swizzled SOURCE chunk

    for (int k0 = 0; k0 < K; k0 += 64) {
#pragma unroll
        for (int r = 0; r < 4; ++r)
            __builtin_amdgcn_global_load_lds(
                (gbl_void*)(Ab + (long)(r * 32 + srow) * K + k0 + sgcol),
                (lds_void*)(As + (r * 256 + wave * 64) * 8), 16, 0, 0);
#pragma unroll
        for (int r = 0; r < 4; ++r)
            __builtin_amdgcn_global_load_lds(
                (gbl_void*)(Bb + (long)(r * 32 + srow) * K + k0 + sgcol),
                (lds_void*)(Bs + (r * 256 + wave * 64) * 8), 16, 0, 0);
        __syncthreads();

        const int arow = lane & 31;
        const int kh   = lane >> 5;                    // k-half: k = kh*8 + j
#pragma unroll
        for (int kk = 0; kk < 4; ++kk) {               // 4 x K=16
            const int c  = kk * 2 + kh;                // logical chunk 0..7
            const int sw = (c ^ (lane & 7)) << 3;      // swizzled read offset
            bf16x8 af[2], bfr[2];
#pragma unroll
            for (int i = 0; i < 2; ++i)
                af[i] = *reinterpret_cast<const bf16x8*>(As + (wm + i * 32 + arow) * 64 + sw);
#pragma unroll
            for (int j = 0; j < 2; ++j)
                bfr[j] = *reinterpret_cast<const bf16x8*>(Bs + (wn + j * 32 + arow) * 64 + sw);
#pragma unroll
            for (int i = 0; i < 2; ++i)
#pragma unroll
                for (int j = 0; j < 2; ++j)
                    acc[i][j] = __builtin_amdgcn_mfma_f32_32x32x16_bf16(af[i], bfr[j], acc[i][j], 0, 0, 0);
        }
        __syncthreads();
    }

    // C/D layout (verified m74/m101): col=lane&31, row=(r&3)+8*(r>>2)+4*(lane>>5)
    const long mbase = bm * 128 + wm + ((lane >> 5) << 2);
    const long nbase = bn * 128 + wn + (lane & 31);
#pragma unroll
    for (int i = 0; i < 2; ++i)
#pragma unroll
        for (int j = 0; j < 2; ++j)
#pragma unroll
            for (int r = 0; r < 16; ++r) {
                const long row = mbase + i * 32 + (r & 3) + 8 * (r >> 2);
                store_c(C, row * (long)N + nbase + j * 32, acc[i][j][r]);
            }
}

// ------------------- per-row head attention + scatter ----------------------
// qkv row m=(b,t): q=e[0,1024), k=e[1024,2048), v=e[2048,3072); h=e/64%16.
// scores[i][j]=0.125*dot64(q_i,k_j); softmax over j; out[i][s]=sum_j a*v.
// Scatter: out[b,t,h,s] -> out3[b, h*128 + t/16, 64*(t%16)+s].
// rows[] is XOR chunk-swizzled: chunk c of 64-elem vector vi at c^(vi&7).
__global__ __launch_bounds__(256) void attn_rowlocal(const unsigned short* __restrict__ qkv,
                                                     unsigned short* __restrict__ out3) {
    __shared__ __align__(16) unsigned short rows[4 * 3072];  // 24 KB, swizzled
    __shared__ float attnS[4][16][17];                       // padded

    const int tid  = threadIdx.x;
    const int lane = tid & 63;
    const int wave = tid >> 6;
    const int m0   = blockIdx.x * 4;

    {   // cooperative load: LDS slot S gets global chunk (S&~7)|((S&7)^((S>>3)&7))
        const uint4* src = reinterpret_cast<const uint4*>(qkv + (long)m0 * 3072);
        uint4* dst = reinterpret_cast<uint4*>(rows);
#pragma unroll
        for (int c = 0; c < 6; ++c) {
            const int S  = c * 256 + tid;
            const int gs = (S & ~7) | ((S & 7) ^ ((S >> 3) & 7));
            dst[S] = src[gs];
        }
    }
    __syncthreads();

    const int m = m0 + wave;
    const int b = m >> 11;
    const int t = m & 2047;
    const unsigned short* rw = rows + wave * 3072;

    // scores: lane handles i = lane&15, j in [(lane>>4)*4, +4)
    const int i  = lane & 15;
    const int j0 = (lane >> 4) << 2;
    float sc[4] = {0.f, 0.f, 0.f, 0.f};
#pragma unroll
    for (int c8 = 0; c8 < 8; ++c8) {
        uint4 qu = *reinterpret_cast<const uint4*>(rw + i * 64 + ((c8 ^ (i & 7)) << 3));
        float qf[8];
        unpack8(qu, qf);
#pragma unroll
        for (int jj = 0; jj < 4; ++jj) {
            const int vi = 16 + j0 + jj;
            uint4 ku = *reinterpret_cast<const uint4*>(rw + vi * 64 + ((c8 ^ (vi & 7)) << 3));
            float kf[8];
            unpack8(ku, kf);
#pragma unroll
            for (int d = 0; d < 8; ++d) sc[jj] += qf[d] * kf[d];
        }
    }
#pragma unroll
    for (int jj = 0; jj < 4; ++jj) sc[jj] *= 0.125f;

    float mx = fmaxf(fmaxf(sc[0], sc[1]), fmaxf(sc[2], sc[3]));
    mx = fmaxf(mx, __shfl_xor(mx, 16));
    mx = fmaxf(mx, __shfl_xor(mx, 32));
    float sum = 0.f;
#pragma unroll
    for (int jj = 0; jj < 4; ++jj) { sc[jj] = __expf(sc[jj] - mx); sum += sc[jj]; }
    sum += __shfl_xor(sum, 16);
    sum += __shfl_xor(sum, 32);
    const float inv = 1.0f / sum;
#pragma unroll
    for (int jj = 0; jj < 4; ++jj) attnS[wave][i][j0 + jj] = sc[jj] * inv;
    __syncthreads();

    // out: lane handles head oi = lane>>2, s chunk s0 = (lane&3)*16
    const int oi = lane >> 2;
    const int s0 = (lane & 3) << 4;
    const int c0 = (lane & 3) << 1;
    float o[16];
#pragma unroll
    for (int ss = 0; ss < 16; ++ss) o[ss] = 0.f;
#pragma unroll
    for (int j = 0; j < 16; ++j) {
        const float a  = attnS[wave][oi][j];
        const int   vi = 32 + j;
        uint4 v0 = *reinterpret_cast<const uint4*>(rw + vi * 64 + (((c0)     ^ (vi & 7)) << 3));
        uint4 v1 = *reinterpret_cast<const uint4*>(rw + vi * 64 + (((c0 + 1) ^ (vi & 7)) << 3));
        float vf[16];
        unpack8(v0, vf);
        unpack8(v1, vf + 8);
#pragma unroll
        for (int ss = 0; ss < 16; ++ss) o[ss] += a * vf[ss];
    }

    uint4 r0, r1;
    r0.x = pack2(o[0],  o[1]);  r0.y = pack2(o[2],  o[3]);
    r0.z = pack2(o[4],  o[5]);  r0.w = pack2(o[6],  o[7]);
    r1.x = pack2(o[8],  o[9]);  r1.y = pack2(o[10], o[11]);
    r1.z = pack2(o[12], o[13]); r1.w = pack2(o[14], o[15]);

    const long base = (long)b * (2048 * 1024)
                    + (long)(oi * 128 + (t >> 4)) * 1024
                    + 64 * (t & 15) + s0;
    *reinterpret_cast<uint4*>(out3 + base)     = r0;
    *reinterpret_cast<uint4*>(out3 + base + 8) = r1;
}

// ------------------------------- launcher ----------------------------------
extern "C" void kernel_launch(void* const* d_in, const int* in_sizes, int n_in,
                              void* d_out, int out_size, void* d_ws, size_t ws_size,
                              hipStream_t stream) {
    const float* x     = (const float*)d_in[0];   // (4,2048,1024)
    const float* Wqkv  = (const float*)d_in[1];   // (3072,1024)
    const float* Wproj = (const float*)d_in[2];   // (1024,1024)
    float* out = (float*)d_out;                   // (4,2048,1024) fp32

    char* ws = (char*)d_ws;
    unsigned short* xb     = (unsigned short*)(ws);               // 16.0 MiB
    unsigned short* wqkvb  = (unsigned short*)(ws + 16777216);    //  6.0 MiB
    unsigned short* wprojb = (unsigned short*)(ws + 23068672);    //  2.0 MiB
    unsigned short* qkvb   = (unsigned short*)(ws + 25165824);    // 48.0 MiB
    unsigned short* out3b  = (unsigned short*)(ws + 75497472);    // 16.0 MiB

    // all three fp32->bf16 casts in one dispatch (3,145,728 float4s)
    cvt_all<<<dim3(12288), dim3(256), 0, stream>>>(x, Wqkv, Wproj, xb, wqkvb, wprojb);

    // qkv = x @ Wqkv^T : M=8192, N=3072, K=1024
    gemm_bt<unsigned short><<<dim3(24, 64), dim3(256), 0, stream>>>(
        xb, wqkvb, qkvb, 8192, 3072, 1024);

    attn_rowlocal<<<dim3(2048), dim3(256), 0, stream>>>(qkvb, out3b);

    // out = out3 @ Wproj^T : M=8192, N=1024, K=1024
    gemm_bt<float><<<dim3(8, 64), dim3(256), 0, stream>>>(
        out3b, wprojb, out, 8192, 1024, 1024);
}

// Round 8
// 196.559 us; speedup vs baseline: 2.3440x; 1.0119x over previous
//
#include <hip/hip_runtime.h>

// ---------------------------------------------------------------------------
// MultiheadSelfAttention (row-local head-mixing variant), MI355X / gfx950.
// Round 8: GEMM templated on BM.  GEMM1 stays 128x128 (3 blk/CU, plateau).
// GEMM2 goes 64x128 -> 1024 blocks = 4/CU (was 512 = 2/CU, grid-limited) for
// better barrier-stall hiding on the short-K GEMM.
// ---------------------------------------------------------------------------

typedef __bf16 bf16x8 __attribute__((ext_vector_type(8)));
typedef float  f32x16 __attribute__((ext_vector_type(16)));

typedef __attribute__((address_space(3))) void       lds_void;
typedef const __attribute__((address_space(1))) void gbl_void;

__device__ __forceinline__ unsigned short f2b(float f) {
    unsigned int u = __builtin_bit_cast(unsigned int, f);
    return (unsigned short)((u + 0x7FFFu + ((u >> 16) & 1u)) >> 16);  // RNE
}
__device__ __forceinline__ unsigned int pack2(float a, float b) {
    return (unsigned int)f2b(a) | ((unsigned int)f2b(b) << 16);
}
__device__ __forceinline__ void unpack8(uint4 u, float* f) {
    unsigned int w[4] = {u.x, u.y, u.z, u.w};
#pragma unroll
    for (int a = 0; a < 4; ++a) {
        union { unsigned int i; float f; } lo, hi;
        lo.i = w[a] << 16;
        hi.i = w[a] & 0xFFFF0000u;
        f[a * 2]     = lo.f;
        f[a * 2 + 1] = hi.f;
    }
}

// ------------------------- fused fp32 -> bf16 cast -------------------------
__global__ __launch_bounds__(256) void cvt_all(const float* __restrict__ x,
                                               const float* __restrict__ wqkv,
                                               const float* __restrict__ wproj,
                                               unsigned short* __restrict__ xb,
                                               unsigned short* __restrict__ wqkvb,
                                               unsigned short* __restrict__ wprojb) {
    int i = blockIdx.x * 256 + threadIdx.x;
    const float* src;
    unsigned short* dst;
    if (i < 2097152)      { src = x;     dst = xb;                   }
    else if (i < 2883584) { src = wqkv;  dst = wqkvb;  i -= 2097152; }
    else                  { src = wproj; dst = wprojb; i -= 2883584; }
    float4 f = reinterpret_cast<const float4*>(src)[i];
    ushort4 u;
    u.x = f2b(f.x); u.y = f2b(f.y); u.z = f2b(f.z); u.w = f2b(f.w);
    reinterpret_cast<ushort4*>(dst)[i] = u;
}

// --------------------------- bf16 NT GEMM ----------------------------------
// C[m,n] = sum_k A[m,k]*B[n,k].  A: MxK rm, B: NxK rm (bf16 bits as ushort).
// Block tile BMx128, BK=64.  4 waves 2x2; wave tile (BM/2)x64 as MIx2 tiles
// of 32x32x16 MFMA (MI = BM/64).  LDS rows = 8 chunks of 16B; chunk c of row
// r at slot c^(r&7) -> conflict-free ds_read_b128 and conflict-free staging.
__device__ __forceinline__ void store_c(float* C, long idx, float v)          { C[idx] = v; }
__device__ __forceinline__ void store_c(unsigned short* C, long idx, float v) { C[idx] = f2b(v); }

template <int BM, typename CT>
__global__ __launch_bounds__(256) void gemm_bt(const unsigned short* __restrict__ A,
                                               const unsigned short* __restrict__ B,
                                               CT* __restrict__ C,
                                               int M, int N, int K) {
    constexpr int MI = BM / 64;                    // 32-row MFMA tiles per wave
    __shared__ __align__(16) unsigned short As[BM * 64];
    __shared__ __align__(16) unsigned short Bs[128 * 64];

    const int tid  = threadIdx.x;
    const int lane = tid & 63;
    const int wave = tid >> 6;
    const long bm  = blockIdx.y;
    const long bn  = blockIdx.x;
    const int wm   = (wave >> 1) * (BM / 2);
    const int wn   = (wave & 1) * 64;

    f32x16 acc[MI][2] = {};

    const unsigned short* Ab = A + bm * BM * (long)K;
    const unsigned short* Bb = B + bn * 128 * (long)K;

    const int srow  = tid >> 3;                        // row within 32-row group
    const int sgcol = ((tid & 7) ^ (srow & 7)) << 3;   // swizzled SOURCE chunk

    for (int k0 = 0; k0 < K; k0 += 64) {
#pragma unroll
        for (int r = 0; r < BM / 32; ++r)
            __builtin_amdgcn_global_load_lds(
                (gbl_void*)(Ab + (long)(r * 32 + srow) * K + k0 + sgcol),
                (lds_void*)(As + (r * 256 + wave * 64) * 8), 16, 0, 0);
#pragma unroll
        for (int r = 0; r < 4; ++r)
            __builtin_amdgcn_global_load_lds(
                (gbl_void*)(Bb + (long)(r * 32 + srow) * K + k0 + sgcol),
                (lds_void*)(Bs + (r * 256 + wave * 64) * 8), 16, 0, 0);
        __syncthreads();

        const int arow = lane & 31;
        const int kh   = lane >> 5;                    // k-half: k = kh*8 + j
#pragma unroll
        for (int kk = 0; kk < 4; ++kk) {               // 4 x K=16
            const int c  = kk * 2 + kh;                // logical chunk 0..7
            const int sw = (c ^ (lane & 7)) << 3;      // swizzled read offset
            bf16x8 af[MI], bfr[2];
#pragma unroll
            for (int i = 0; i < MI; ++i)
                af[i] = *reinterpret_cast<const bf16x8*>(As + (wm + i * 32 + arow) * 64 + sw);
#pragma unroll
            for (int j = 0; j < 2; ++j)
                bfr[j] = *reinterpret_cast<const bf16x8*>(Bs + (wn + j * 32 + arow) * 64 + sw);
#pragma unroll
            for (int i = 0; i < MI; ++i)
#pragma unroll
                for (int j = 0; j < 2; ++j)
                    acc[i][j] = __builtin_amdgcn_mfma_f32_32x32x16_bf16(af[i], bfr[j], acc[i][j], 0, 0, 0);
        }
        __syncthreads();
    }

    // C/D layout (verified m74/m101): col=lane&31, row=(r&3)+8*(r>>2)+4*(lane>>5)
    const long mbase = bm * BM + wm + ((lane >> 5) << 2);
    const long nbase = bn * 128 + wn + (lane & 31);
#pragma unroll
    for (int i = 0; i < MI; ++i)
#pragma unroll
        for (int j = 0; j < 2; ++j)
#pragma unroll
            for (int r = 0; r < 16; ++r) {
                const long row = mbase + i * 32 + (r & 3) + 8 * (r >> 2);
                store_c(C, row * (long)N + nbase + j * 32, acc[i][j][r]);
            }
}

// ------------------- per-row head attention + scatter ----------------------
// qkv row m=(b,t): q=e[0,1024), k=e[1024,2048), v=e[2048,3072); h=e/64%16.
// scores[i][j]=0.125*dot64(q_i,k_j); softmax over j; out[i][s]=sum_j a*v.
// Scatter: out[b,t,h,s] -> out3[b, h*128 + t/16, 64*(t%16)+s].
// rows[] is XOR chunk-swizzled: chunk c of 64-elem vector vi at c^(vi&7).
__global__ __launch_bounds__(256) void attn_rowlocal(const unsigned short* __restrict__ qkv,
                                                     unsigned short* __restrict__ out3) {
    __shared__ __align__(16) unsigned short rows[4 * 3072];  // 24 KB, swizzled
    __shared__ float attnS[4][16][17];                       // padded

    const int tid  = threadIdx.x;
    const int lane = tid & 63;
    const int wave = tid >> 6;
    const int m0   = blockIdx.x * 4;

    {   // cooperative load: LDS slot S gets global chunk (S&~7)|((S&7)^((S>>3)&7))
        const uint4* src = reinterpret_cast<const uint4*>(qkv + (long)m0 * 3072);
        uint4* dst = reinterpret_cast<uint4*>(rows);
#pragma unroll
        for (int c = 0; c < 6; ++c) {
            const int S  = c * 256 + tid;
            const int gs = (S & ~7) | ((S & 7) ^ ((S >> 3) & 7));
            dst[S] = src[gs];
        }
    }
    __syncthreads();

    const int m = m0 + wave;
    const int b = m >> 11;
    const int t = m & 2047;
    const unsigned short* rw = rows + wave * 3072;

    // scores: lane handles i = lane&15, j in [(lane>>4)*4, +4)
    const int i  = lane & 15;
    const int j0 = (lane >> 4) << 2;
    float sc[4] = {0.f, 0.f, 0.f, 0.f};
#pragma unroll
    for (int c8 = 0; c8 < 8; ++c8) {
        uint4 qu = *reinterpret_cast<const uint4*>(rw + i * 64 + ((c8 ^ (i & 7)) << 3));
        float qf[8];
        unpack8(qu, qf);
#pragma unroll
        for (int jj = 0; jj < 4; ++jj) {
            const int vi = 16 + j0 + jj;
            uint4 ku = *reinterpret_cast<const uint4*>(rw + vi * 64 + ((c8 ^ (vi & 7)) << 3));
            float kf[8];
            unpack8(ku, kf);
#pragma unroll
            for (int d = 0; d < 8; ++d) sc[jj] += qf[d] * kf[d];
        }
    }
#pragma unroll
    for (int jj = 0; jj < 4; ++jj) sc[jj] *= 0.125f;

    float mx = fmaxf(fmaxf(sc[0], sc[1]), fmaxf(sc[2], sc[3]));
    mx = fmaxf(mx, __shfl_xor(mx, 16));
    mx = fmaxf(mx, __shfl_xor(mx, 32));
    float sum = 0.f;
#pragma unroll
    for (int jj = 0; jj < 4; ++jj) { sc[jj] = __expf(sc[jj] - mx); sum += sc[jj]; }
    sum += __shfl_xor(sum, 16);
    sum += __shfl_xor(sum, 32);
    const float inv = 1.0f / sum;
#pragma unroll
    for (int jj = 0; jj < 4; ++jj) attnS[wave][i][j0 + jj] = sc[jj] * inv;
    __syncthreads();

    // out: lane handles head oi = lane>>2, s chunk s0 = (lane&3)*16
    const int oi = lane >> 2;
    const int s0 = (lane & 3) << 4;
    const int c0 = (lane & 3) << 1;
    float o[16];
#pragma unroll
    for (int ss = 0; ss < 16; ++ss) o[ss] = 0.f;
#pragma unroll
    for (int j = 0; j < 16; ++j) {
        const float a  = attnS[wave][oi][j];
        const int   vi = 32 + j;
        uint4 v0 = *reinterpret_cast<const uint4*>(rw + vi * 64 + (((c0)     ^ (vi & 7)) << 3));
        uint4 v1 = *reinterpret_cast<const uint4*>(rw + vi * 64 + (((c0 + 1) ^ (vi & 7)) << 3));
        float vf[16];
        unpack8(v0, vf);
        unpack8(v1, vf + 8);
#pragma unroll
        for (int ss = 0; ss < 16; ++ss) o[ss] += a * vf[ss];
    }

    uint4 r0, r1;
    r0.x = pack2(o[0],  o[1]);  r0.y = pack2(o[2],  o[3]);
    r0.z = pack2(o[4],  o[5]);  r0.w = pack2(o[6],  o[7]);
    r1.x = pack2(o[8],  o[9]);  r1.y = pack2(o[10], o[11]);
    r1.z = pack2(o[12], o[13]); r1.w = pack2(o[14], o[15]);

    const long base = (long)b * (2048 * 1024)
                    + (long)(oi * 128 + (t >> 4)) * 1024
                    + 64 * (t & 15) + s0;
    *reinterpret_cast<uint4*>(out3 + base)     = r0;
    *reinterpret_cast<uint4*>(out3 + base + 8) = r1;
}

// ------------------------------- launcher ----------------------------------
extern "C" void kernel_launch(void* const* d_in, const int* in_sizes, int n_in,
                              void* d_out, int out_size, void* d_ws, size_t ws_size,
                              hipStream_t stream) {
    const float* x     = (const float*)d_in[0];   // (4,2048,1024)
    const float* Wqkv  = (const float*)d_in[1];   // (3072,1024)
    const float* Wproj = (const float*)d_in[2];   // (1024,1024)
    float* out = (float*)d_out;                   // (4,2048,1024) fp32

    char* ws = (char*)d_ws;
    unsigned short* xb     = (unsigned short*)(ws);               // 16.0 MiB
    unsigned short* wqkvb  = (unsigned short*)(ws + 16777216);    //  6.0 MiB
    unsigned short* wprojb = (unsigned short*)(ws + 23068672);    //  2.0 MiB
    unsigned short* qkvb   = (unsigned short*)(ws + 25165824);    // 48.0 MiB
    unsigned short* out3b  = (unsigned short*)(ws + 75497472);    // 16.0 MiB

    // all three fp32->bf16 casts in one dispatch (3,145,728 float4s)
    cvt_all<<<dim3(12288), dim3(256), 0, stream>>>(x, Wqkv, Wproj, xb, wqkvb, wprojb);

    // qkv = x @ Wqkv^T : M=8192, N=3072, K=1024  (128x128 tiles, 3 blk/CU)
    gemm_bt<128, unsigned short><<<dim3(24, 64), dim3(256), 0, stream>>>(
        xb, wqkvb, qkvb, 8192, 3072, 1024);

    attn_rowlocal<<<dim3(2048), dim3(256), 0, stream>>>(qkvb, out3b);

    // out = out3 @ Wproj^T : M=8192, N=1024, K=1024  (64x128 tiles, 4 blk/CU)
    gemm_bt<64, float><<<dim3(8, 128), dim3(256), 0, stream>>>(
        out3b, wprojb, out, 8192, 1024, 1024);
}